// Round 1
// baseline (387.155 us; speedup 1.0000x reference)
//
#include <hip/hip_runtime.h>

// EmbeddingFusionLayer: out_users[n,e]   = sum_v softmax(uw)[v] * view_users[v,n,e]
//                       out_products[m,e]= sum_v softmax(pw)[v] * view_products[v,m,e]
// Pure HBM-BW-bound weighted sum over 4 views. float4 vectorized, grid-stride.

constexpr int NVIEW = 4;
constexpr long long N_USER = 1000000LL;
constexpr long long N_PRODUCT = 500000LL;
constexpr int EMB = 64;

__global__ __launch_bounds__(256) void fused_view_sum(
    const float* __restrict__ vu,
    const float* __restrict__ vp,
    const float* __restrict__ uwp,
    const float* __restrict__ pwp,
    float* __restrict__ out)
{
    // ---- softmax of the two 4-element weight vectors, per-thread (uniform, cheap)
    float u0 = uwp[0], u1 = uwp[1], u2 = uwp[2], u3 = uwp[3];
    float um = fmaxf(fmaxf(u0, u1), fmaxf(u2, u3));
    float ue0 = expf(u0 - um), ue1 = expf(u1 - um), ue2 = expf(u2 - um), ue3 = expf(u3 - um);
    float uinv = 1.0f / (ue0 + ue1 + ue2 + ue3);
    const float w0 = ue0 * uinv, w1 = ue1 * uinv, w2 = ue2 * uinv, w3 = ue3 * uinv;

    float p0 = pwp[0], p1 = pwp[1], p2 = pwp[2], p3 = pwp[3];
    float pm = fmaxf(fmaxf(p0, p1), fmaxf(p2, p3));
    float pe0 = expf(p0 - pm), pe1 = expf(p1 - pm), pe2 = expf(p2 - pm), pe3 = expf(p3 - pm);
    float pinv = 1.0f / (pe0 + pe1 + pe2 + pe3);
    const float q0 = pe0 * pinv, q1 = pe1 * pinv, q2 = pe2 * pinv, q3 = pe3 * pinv;

    // ---- float4 work items: users region then products region
    const int NU4 = (int)(N_USER * EMB / 4);      // 16,000,000 float4 per user view
    const int NP4 = (int)(N_PRODUCT * EMB / 4);   //  8,000,000 float4 per product view
    const int total = NU4 + NP4;                  // 24,000,000

    const float4* __restrict__ vu4 = (const float4*)vu;
    const float4* __restrict__ vp4 = (const float4*)vp;
    float4* __restrict__ ou4 = (float4*)out;                          // users out
    float4* __restrict__ op4 = (float4*)(out + N_USER * EMB);         // products out

    const int stride = gridDim.x * blockDim.x;
    for (int i = blockIdx.x * blockDim.x + threadIdx.x; i < total; i += stride) {
        if (i < NU4) {
            float4 a = vu4[i];
            float4 b = vu4[i + NU4];
            float4 c = vu4[i + 2 * NU4];
            float4 d = vu4[i + 3 * NU4];
            float4 r;
            r.x = fmaf(w0, a.x, fmaf(w1, b.x, fmaf(w2, c.x, w3 * d.x)));
            r.y = fmaf(w0, a.y, fmaf(w1, b.y, fmaf(w2, c.y, w3 * d.y)));
            r.z = fmaf(w0, a.z, fmaf(w1, b.z, fmaf(w2, c.z, w3 * d.z)));
            r.w = fmaf(w0, a.w, fmaf(w1, b.w, fmaf(w2, c.w, w3 * d.w)));
            ou4[i] = r;
        } else {
            int j = i - NU4;
            float4 a = vp4[j];
            float4 b = vp4[j + NP4];
            float4 c = vp4[j + 2 * NP4];
            float4 d = vp4[j + 3 * NP4];
            float4 r;
            r.x = fmaf(q0, a.x, fmaf(q1, b.x, fmaf(q2, c.x, q3 * d.x)));
            r.y = fmaf(q0, a.y, fmaf(q1, b.y, fmaf(q2, c.y, q3 * d.y)));
            r.z = fmaf(q0, a.z, fmaf(q1, b.z, fmaf(q2, c.z, q3 * d.z)));
            r.w = fmaf(q0, a.w, fmaf(q1, b.w, fmaf(q2, c.w, q3 * d.w)));
            op4[j] = r;
        }
    }
}

extern "C" void kernel_launch(void* const* d_in, const int* in_sizes, int n_in,
                              void* d_out, int out_size, void* d_ws, size_t ws_size,
                              hipStream_t stream) {
    const float* vu = (const float*)d_in[0];   // [4, 1e6, 64]
    const float* vp = (const float*)d_in[1];   // [4, 5e5, 64]
    const float* uw = (const float*)d_in[2];   // [1, 4]
    const float* pw = (const float*)d_in[3];   // [1, 4]
    float* out = (float*)d_out;                // [1e6*64 + 5e5*64] concat

    // memory-bound: cap grid at ~8 blocks/CU * 256 CUs, grid-stride the rest
    const int block = 256;
    const int grid = 2048;
    fused_view_sum<<<grid, block, 0, stream>>>(vu, vp, uw, pw, out);
}